// Round 13
// baseline (558.628 us; speedup 1.0000x reference)
//
#include <hip/hip_runtime.h>
#include <cstdint>
#include <cstddef>

#define NN 50000
#define NE 800000
#define NEPAD (NE + 3 * NN)   // CSR rows padded to multiple of 4
#define HID 128
#define NGRAPH 64
#define NCLASS 10
#define LHID 3
#define NREP 8                // deg counter replicas

// 16-row fragment blocks: 50000/16 = 3125 exact; GEMM covers 782*4 = 3128
#define ROWBLK 3125
#define ROWBLK_PAD 3128
#define GEMM_GRID 782         // 64-row tiles
#define FILL_GRID 3125        // 800000 / 256
#define FRONT_DEG 3125        // deg blocks (FIRST: they are the long pole)
#define FRONT_A 3125          // convA blocks
#define FRONT_B 56            // convB blocks (8 x 7 mats)
#define FRONT_GRID (FRONT_DEG + FRONT_A + FRONT_B)

// 1/sqrt(1+1e-5), computed in double, rounded to f32
static constexpr float BN_INV = 0.9999950000374996f;

typedef __attribute__((ext_vector_type(8))) __bf16 bf16x8;
typedef __attribute__((ext_vector_type(4))) float floatx4;

// ---------------- bf16 split helpers ----------------

__device__ __forceinline__ unsigned int f32_to_bf16_rne(float f) {
    unsigned int u = __float_as_uint(f);
    return (u + 0x7FFFu + ((u >> 16) & 1u)) >> 16;
}
__device__ __forceinline__ float bf16_to_f32(unsigned int h) {
    return __uint_as_float(h << 16);
}
__device__ __forceinline__ void split2(float a, float b, unsigned int& hi,
                                       unsigned int& lo) {
    unsigned int h0 = f32_to_bf16_rne(a), h1 = f32_to_bf16_rne(b);
    unsigned int l0 = f32_to_bf16_rne(a - bf16_to_f32(h0));
    unsigned int l1 = f32_to_bf16_rne(b - bf16_to_f32(h1));
    hi = h0 | (h1 << 16);
    lo = l0 | (l1 << 16);
}

__device__ __forceinline__ void gl2lds16(const void* g, void* l) {
    __builtin_amdgcn_global_load_lds((__attribute__((address_space(1))) void*)g,
                                     (__attribute__((address_space(3))) void*)l,
                                     16, 0, 0);
}

// ---------------- front: deg (first!) + convA + convB ----------------------

__global__ void k_front(const float* __restrict__ x, unsigned short* __restrict__ xH,
                        unsigned short* __restrict__ xL,
                        const float* __restrict__ W0, const float* __restrict__ Wh,
                        const float* __restrict__ Rh, unsigned short* __restrict__ bH,
                        unsigned short* __restrict__ bL,
                        const int* __restrict__ ei, int* __restrict__ deg8,
                        int* __restrict__ eslot) {
    const int b = blockIdx.x;
    const int tid = threadIdx.x;
    if (b < FRONT_DEG) {
        // deg histogram with 8x replicated counters (contention /8) + slot record
        int e = b * 256 + tid;                  // < 800000 exact
        int d = ei[NE + e];
        int rep = e & (NREP - 1);
        eslot[e] = atomicAdd(&deg8[rep * NN + d], 1);
    } else if (b < FRONT_DEG + FRONT_A) {
        // convA: x (f32 row-major) -> swizzled bf16 hi/lo A-fragments.
        int u = (b - FRONT_DEG) * 256 + tid;
        int lane = u & 63;
        int blk = u >> 6;
        int kblk = blk & 3;
        int rowBlock = blk >> 2;
        int m = rowBlock * 16 + (lane & 15);
        int k = kblk * 32 + (lane >> 4) * 8;
        const float4* p = (const float4*)&x[(size_t)m * 128 + k];
        float4 v0 = p[0];
        float4 v1 = p[1];
        float vals[8] = {v0.x, v0.y, v0.z, v0.w, v1.x, v1.y, v1.z, v1.w};
        union { unsigned int i[4]; uint4 v; } H, L;
#pragma unroll
        for (int j = 0; j < 4; ++j) split2(vals[2 * j], vals[2 * j + 1], H.i[j], L.i[j]);
        *(uint4*)&xH[(size_t)u * 8] = H.v;
        *(uint4*)&xL[(size_t)u * 8] = L.v;
    } else {
        // convB: W [k][n] f32 -> swizzled fragments; 7 matrices.
        int cb = b - FRONT_DEG - FRONT_A;
        int mat = cb >> 3;
        const float* src = (mat == 0) ? W0
                         : (mat <= 3) ? (Wh + (size_t)(mat - 1) * 16384)
                                      : (Rh + (size_t)(mat - 4) * 16384);
        int u = (cb & 7) * 256 + tid;  // 0..2047
        int lane = u & 63;
        int blk = u >> 6;
        int kblk = blk & 3;
        int nb = blk >> 2;
        int n = nb * 16 + (lane & 15);
        int k = kblk * 32 + (lane >> 4) * 8;
        union { unsigned int i[4]; uint4 v; } H, L;
#pragma unroll
        for (int j = 0; j < 4; ++j) {
            float a = src[(size_t)(k + 2 * j) * 128 + n];
            float c = src[(size_t)(k + 2 * j + 1) * 128 + n];
            split2(a, c, H.i[j], L.i[j]);
        }
        size_t base = (size_t)mat * 16384 + (size_t)u * 8;
        *(uint4*)&bH[base] = H.v;
        *(uint4*)&bL[base] = L.v;
    }
}

// ---------------- scan1: replica reduce + per-rep offsets + dinv + bsum -----

__global__ void k_scan1(const int* __restrict__ deg8, int* __restrict__ degT,
                        int* __restrict__ degOff, float* __restrict__ dinv,
                        int* __restrict__ bsum) {
    __shared__ int s[256];
    int i = blockIdx.x * 256 + threadIdx.x;
    int dsum = 0;
    if (i < NN) {
        int off[NREP];
#pragma unroll
        for (int r = 0; r < NREP; ++r) {
            off[r] = dsum;
            dsum += deg8[r * NN + i];
        }
#pragma unroll
        for (int r = 0; r < NREP; ++r) degOff[i * NREP + r] = off[r];
        degT[i] = dsum;
        dinv[i] = rsqrtf((float)(dsum + 1));  // +1 self-loop
    }
    s[threadIdx.x] = (dsum + 3) & ~3;
    __syncthreads();
    for (int o = 128; o > 0; o >>= 1) {
        if (threadIdx.x < o) s[threadIdx.x] += s[threadIdx.x + o];
        __syncthreads();
    }
    if (threadIdx.x == 0) bsum[blockIdx.x] = s[0];
}

// ---------------- scan3: rowptr (inlines scan2) + CSR pad zeroing ----------

__global__ void k_scan3(const int* __restrict__ degT, const int* __restrict__ bsum,
                        int* __restrict__ rowptr, int2* __restrict__ pairs) {
    __shared__ int s[256];
    __shared__ int offS;
    const int bid = blockIdx.x;
    s[threadIdx.x] = (threadIdx.x < bid) ? bsum[threadIdx.x] : 0;
    __syncthreads();
    for (int o = 128; o > 0; o >>= 1) {
        if (threadIdx.x < o) s[threadIdx.x] += s[threadIdx.x + o];
        __syncthreads();
    }
    if (threadIdx.x == 0) offS = s[0];
    __syncthreads();
    const int off = offS;
    __syncthreads();
    int i = bid * 256 + threadIdx.x;
    int d = (i < NN) ? degT[i] : 0;
    int v = (d + 3) & ~3;
    s[threadIdx.x] = v;
    __syncthreads();
    for (int o = 1; o < 256; o <<= 1) {
        int tv = (threadIdx.x >= o) ? s[threadIdx.x - o] : 0;
        __syncthreads();
        s[threadIdx.x] += tv;
        __syncthreads();
    }
    if (i < NN) {
        int rp = off + s[threadIdx.x] - v;  // exclusive
        rowptr[i] = rp;
        // zero the pad slots (<=3 per row, single 8B store each)
        for (int p = rp + d; p < rp + v; ++p) pairs[p] = make_int2(0, 0);
    }
}

// ---------------- MFMA GEMM: C1 = A @ B1 [, C2 = A @ B2], split-bf16 --------
// Inline body (device-function/generic-LDS form ICEs clang). FILL=true adds
// CSR-fill blocks past GEMM_GRID. 64x128 tile, 4 waves 2x2, wave tile 32x64.

template <int NB, bool FILL>
__global__ __launch_bounds__(256, 3) void k_gemm_mfma(
    const unsigned short* __restrict__ Ahi, const unsigned short* __restrict__ Alo,
    const unsigned short* __restrict__ B1hi, const unsigned short* __restrict__ B1lo,
    const unsigned short* __restrict__ B2hi, const unsigned short* __restrict__ B2lo,
    float* __restrict__ C1, float* __restrict__ C2,
    const int* __restrict__ ei, const int* __restrict__ rowptr,
    const int* __restrict__ eslot, const int* __restrict__ degOff,
    const float* __restrict__ dinv, int2* __restrict__ pairs) {
    __shared__ unsigned short lds[(1 + 2 * NB) * 4096];
    if (FILL && blockIdx.x >= GEMM_GRID) {
        int e = (blockIdx.x - GEMM_GRID) * 256 + threadIdx.x;  // < 800000 exact
        int s = ei[e];
        int d = ei[NE + e];
        int rep = e & (NREP - 1);
        int p = rowptr[d] + degOff[d * NREP + rep] + eslot[e];
        pairs[p] = make_int2(s, __float_as_int(dinv[s]));  // single 8B store
        return;
    }
    unsigned short* AhiS = lds;             // 2048
    unsigned short* AloS = lds + 2048;      // 2048
    unsigned short* B1hiS = lds + 4096;     // 4096
    unsigned short* B1loS = lds + 8192;     // 4096
    unsigned short* B2hiS = lds + 12288;    // NB==2 only
    unsigned short* B2loS = lds + 16384;

    const int tid = threadIdx.x;
    const int wave = tid >> 6;
    const int lane = tid & 63;
    const int wm = wave & 1;
    const int wn = wave >> 1;
    const int rb0 = blockIdx.x * 4;         // first 16-row block

    floatx4 acc1[2][4], acc2[2][4];
    floatx4 zero = {0.f, 0.f, 0.f, 0.f};
#pragma unroll
    for (int i = 0; i < 2; ++i)
#pragma unroll
        for (int j = 0; j < 4; ++j) { acc1[i][j] = zero; if (NB == 2) acc2[i][j] = zero; }

    for (int kc = 0; kc < 4; ++kc) {
        const int nit = (NB == 2) ? 10 : 6;  // units: A 8 + B 16*NB, / 4 waves
#pragma unroll
        for (int it = 0; it < nit; ++it) {
            int i = it * 4 + wave;
            const unsigned short* src;
            unsigned short* dst;
            if (i < 4)       { src = Ahi  + ((size_t)(rb0 + i) * 4 + kc) * 512;       dst = AhiS  + i * 512; }
            else if (i < 8)  { int rb = i - 4;  src = Alo  + ((size_t)(rb0 + rb) * 4 + kc) * 512; dst = AloS  + rb * 512; }
            else if (i < 16) { int nb = i - 8;  src = B1hi + ((size_t)nb * 4 + kc) * 512;         dst = B1hiS + nb * 512; }
            else if (i < 24) { int nb = i - 16; src = B1lo + ((size_t)nb * 4 + kc) * 512;         dst = B1loS + nb * 512; }
            else if (i < 32) { int nb = i - 24; src = B2hi + ((size_t)nb * 4 + kc) * 512;         dst = B2hiS + nb * 512; }
            else             { int nb = i - 32; src = B2lo + ((size_t)nb * 4 + kc) * 512;         dst = B2loS + nb * 512; }
            gl2lds16(src + (size_t)lane * 8, dst);
        }
        __syncthreads();

        bf16x8 aH[2], aL[2], bH[4], bL[4];
#pragma unroll
        for (int t = 0; t < 2; ++t)
            aH[t] = *(const bf16x8*)(AhiS + (wm * 2 + t) * 512 + lane * 8);
#pragma unroll
        for (int t = 0; t < 4; ++t)
            bH[t] = *(const bf16x8*)(B1hiS + (wn * 4 + t) * 512 + lane * 8);
#pragma unroll
        for (int tm = 0; tm < 2; ++tm)
#pragma unroll
            for (int tn = 0; tn < 4; ++tn)
                acc1[tm][tn] = __builtin_amdgcn_mfma_f32_16x16x32_bf16(
                    aH[tm], bH[tn], acc1[tm][tn], 0, 0, 0);
#pragma unroll
        for (int t = 0; t < 4; ++t)
            bL[t] = *(const bf16x8*)(B1loS + (wn * 4 + t) * 512 + lane * 8);
#pragma unroll
        for (int tm = 0; tm < 2; ++tm)
#pragma unroll
            for (int tn = 0; tn < 4; ++tn)
                acc1[tm][tn] = __builtin_amdgcn_mfma_f32_16x16x32_bf16(
                    aH[tm], bL[tn], acc1[tm][tn], 0, 0, 0);
#pragma unroll
        for (int t = 0; t < 2; ++t)
            aL[t] = *(const bf16x8*)(AloS + (wm * 2 + t) * 512 + lane * 8);
#pragma unroll
        for (int tm = 0; tm < 2; ++tm)
#pragma unroll
            for (int tn = 0; tn < 4; ++tn)
                acc1[tm][tn] = __builtin_amdgcn_mfma_f32_16x16x32_bf16(
                    aL[tm], bH[tn], acc1[tm][tn], 0, 0, 0);
        if (NB == 2) {
#pragma unroll
            for (int t = 0; t < 4; ++t)
                bH[t] = *(const bf16x8*)(B2hiS + (wn * 4 + t) * 512 + lane * 8);
#pragma unroll
            for (int tm = 0; tm < 2; ++tm)
#pragma unroll
                for (int tn = 0; tn < 4; ++tn)
                    acc2[tm][tn] = __builtin_amdgcn_mfma_f32_16x16x32_bf16(
                        aH[tm], bH[tn], acc2[tm][tn], 0, 0, 0);
#pragma unroll
            for (int tm = 0; tm < 2; ++tm)
#pragma unroll
                for (int tn = 0; tn < 4; ++tn)
                    acc2[tm][tn] = __builtin_amdgcn_mfma_f32_16x16x32_bf16(
                        aL[tm], bH[tn], acc2[tm][tn], 0, 0, 0);
#pragma unroll
            for (int t = 0; t < 4; ++t)
                bL[t] = *(const bf16x8*)(B2loS + (wn * 4 + t) * 512 + lane * 8);
#pragma unroll
            for (int tm = 0; tm < 2; ++tm)
#pragma unroll
                for (int tn = 0; tn < 4; ++tn)
                    acc2[tm][tn] = __builtin_amdgcn_mfma_f32_16x16x32_bf16(
                        aH[tm], bL[tn], acc2[tm][tn], 0, 0, 0);
        }
        __syncthreads();
    }

    // epilogue: C/D layout col = lane&15, row = (lane>>4)*4 + r
    const int quad = lane >> 4;
    const int col0 = lane & 15;
    const int rowBase = blockIdx.x * 64 + wm * 32;
#pragma unroll
    for (int tm = 0; tm < 2; ++tm) {
#pragma unroll
        for (int tn = 0; tn < 4; ++tn) {
            int c = wn * 64 + tn * 16 + col0;
#pragma unroll
            for (int r = 0; r < 4; ++r) {
                int row = rowBase + tm * 16 + quad * 4 + r;
                if (row < NN) {
                    C1[(size_t)row * 128 + c] = acc1[tm][tn][r];
                    if (NB == 2) C2[(size_t)row * 128 + c] = acc2[tm][tn][r];
                }
            }
        }
    }
}

// ---------------- SpMM + epilogue ------------------------------------------
// Block = 16 nodes via 16 WAVES (1024 threads), ONE node per wave. Lane ->
// features (2l,2l+1); one 512 B contiguous row per gather instr; unroll 2 ->
// 8 rows in flight/wave. Metadata = interleaved (col,w) 8B pairs.
// non-LAST: LDS-staged swizzled bf16 hi/lo output. LAST: fused pool.

template <bool RES, bool LAST>
__global__ __launch_bounds__(1024) void k_spmm(const float* __restrict__ t,
                                               const float* __restrict__ r,
                                               const int* __restrict__ rowptr,
                                               const int* __restrict__ degT,
                                               const int2* __restrict__ pairs,
                                               const float* __restrict__ dinv,
                                               const float* __restrict__ bias,
                                               const float* __restrict__ gamma,
                                               const float* __restrict__ beta,
                                               unsigned short* __restrict__ hHi,
                                               unsigned short* __restrict__ hLo,
                                               const int* __restrict__ batch,
                                               float* __restrict__ pooled) {
    __shared__ unsigned short shH[16][136];  // non-LAST only (+8 shorts pad)
    __shared__ unsigned short shL[16][136];
    __shared__ float shP[16][64][2];         // LAST only: per-wave partials
    const int lane = threadIdx.x & 63;
    const int wave = threadIdx.x >> 6;       // 0..15 = node within block
    const int f = lane * 2;
    const int node = blockIdx.x * 16 + wave; // grid = NN/16 exact

    const float2 bv = *(const float2*)&bias[f];
    const float2 gv = *(const float2*)&gamma[f];
    const float2 ev = *(const float2*)&beta[f];

    const int start = rowptr[node];          // multiple of 4 -> 32B-aligned pairs
    const int cnt4 = (degT[node] + 3) >> 2;
    float ax = 0.f, ay = 0.f;
#pragma unroll 2
    for (int q = 0; q < cnt4; ++q) {
        int4 p0 = *(const int4*)&pairs[start + q * 4];      // c0,w0,c1,w1
        int4 p1 = *(const int4*)&pairs[start + q * 4 + 2];  // c2,w2,c3,w3
        float2 v0 = *(const float2*)&t[(size_t)p0.x * 128 + f];
        float2 v1 = *(const float2*)&t[(size_t)p0.z * 128 + f];
        float2 v2 = *(const float2*)&t[(size_t)p1.x * 128 + f];
        float2 v3 = *(const float2*)&t[(size_t)p1.z * 128 + f];
        float w0 = __int_as_float(p0.y), w1 = __int_as_float(p0.w);
        float w2 = __int_as_float(p1.y), w3 = __int_as_float(p1.w);
        ax = fmaf(w0, v0.x, ax); ay = fmaf(w0, v0.y, ay);
        ax = fmaf(w1, v1.x, ax); ay = fmaf(w1, v1.y, ay);
        ax = fmaf(w2, v2.x, ax); ay = fmaf(w2, v2.y, ay);
        ax = fmaf(w3, v3.x, ax); ay = fmaf(w3, v3.y, ay);
    }
    const float di = dinv[node];
    const float dii = di * di;
    float2 tv = *(const float2*)&t[(size_t)node * 128 + f];
    float cx = di * ax + dii * tv.x + bv.x;
    float cy = di * ay + dii * tv.y + bv.y;
    if (RES) {
        float2 rv = *(const float2*)&r[(size_t)node * 128 + f];
        cx += rv.x;
        cy += rv.y;
    }
    const float ox = fmaxf(cx * (BN_INV * gv.x) + ev.x, 0.f);
    const float oy = fmaxf(cy * (BN_INV * gv.y) + ev.y, 0.f);

    if (LAST) {
        bool uni = (batch[blockIdx.x * 16] == batch[blockIdx.x * 16 + 15]);
        if (uni) {
            shP[wave][lane][0] = ox;
            shP[wave][lane][1] = oy;
            __syncthreads();
            if (wave == 0) {
                float a = shP[0][lane][0], b = shP[0][lane][1];
#pragma unroll
                for (int w = 1; w < 16; ++w) {
                    a = fmaxf(a, shP[w][lane][0]);
                    b = fmaxf(b, shP[w][lane][1]);
                }
                int g = batch[blockIdx.x * 16];
                atomicMax((unsigned int*)&pooled[g * 128 + f], __float_as_uint(a));
                atomicMax((unsigned int*)&pooled[g * 128 + f + 1], __float_as_uint(b));
            }
        } else {
            int g = batch[node];
            atomicMax((unsigned int*)&pooled[g * 128 + f], __float_as_uint(ox));
            atomicMax((unsigned int*)&pooled[g * 128 + f + 1], __float_as_uint(oy));
        }
        return;
    }

    unsigned int H, L;
    split2(ox, oy, H, L);
    ((unsigned int*)&shH[wave][0])[lane] = H;
    ((unsigned int*)&shL[wave][0])[lane] = L;
    __syncthreads();

    // emit 4 hi + 4 lo units (1 KB each), fully coalesced; waves 0-7 emit.
    const int u = threadIdx.x >> 6;
    const int l = threadIdx.x & 63;
    const int m = l & 15;
    const int kg = l >> 4;
    if (u < 4) {
        uint4 H4 = *(const uint4*)&shH[m][u * 32 + kg * 8];
        ((uint4*)hHi)[((size_t)blockIdx.x * 4 + u) * 64 + l] = H4;
    } else if (u < 8) {
        int uu = u - 4;
        uint4 L4 = *(const uint4*)&shL[m][uu * 32 + kg * 8];
        ((uint4*)hLo)[((size_t)blockIdx.x * 4 + uu) * 64 + l] = L4;
    }
}

// ---------------- MLP head (64 parallel blocks) ----------------

__global__ void k_head(const float* __restrict__ pooled, const float* __restrict__ mW1,
                       const float* __restrict__ mb1, const float* __restrict__ mW2,
                       const float* __restrict__ mb2, float* __restrict__ out) {
    __shared__ float p[128];
    __shared__ float z[128];
    int g = blockIdx.x;
    int j = threadIdx.x;  // 128 threads
    p[j] = pooled[g * 128 + j];
    __syncthreads();
    float a = mb1[j];
#pragma unroll 8
    for (int k = 0; k < 128; ++k) a += p[k] * mW1[k * 128 + j];
    z[j] = fmaxf(a, 0.f);
    __syncthreads();
    if (j < NCLASS) {
        float o = mb2[j];
#pragma unroll 8
        for (int k = 0; k < 128; ++k) o += z[k] * mW2[k * NCLASS + j];
        out[g * NCLASS + j] = o;
    }
}

// ---------------- launcher ----------------

extern "C" void kernel_launch(void* const* d_in, const int* in_sizes, int n_in,
                              void* d_out, int out_size, void* d_ws, size_t ws_size,
                              hipStream_t stream) {
    const float* x   = (const float*)d_in[0];
    const int*   ei  = (const int*)d_in[1];
    const int* batch = (const int*)d_in[2];
    const float* W0  = (const float*)d_in[3];
    const float* b0  = (const float*)d_in[4];
    const float* g0  = (const float*)d_in[5];
    const float* be0 = (const float*)d_in[6];
    const float* Wh  = (const float*)d_in[7];
    const float* bh  = (const float*)d_in[8];
    const float* gh  = (const float*)d_in[9];
    const float* beh = (const float*)d_in[10];
    const float* Rh  = (const float*)d_in[11];
    const float* mW1 = (const float*)d_in[12];
    const float* mb1 = (const float*)d_in[13];
    const float* mW2 = (const float*)d_in[14];
    const float* mb2 = (const float*)d_in[15];
    float* out = (float*)d_out;

    char* ws = (char*)d_ws;
    size_t off = 0;
    auto alloc = [&](size_t bytes) -> void* {
        void* p = ws + off;
        off += (bytes + 255) & ~(size_t)255;
        return p;
    };
    // deg8 + pooled adjacent -> single memset covers both
    int*   deg8   = (int*)alloc((size_t)NREP * NN * 4);
    float* pooled = (float*)alloc((size_t)NGRAPH * HID * 4);
    size_t zspan = (size_t)((char*)pooled - (char*)deg8) + (size_t)NGRAPH * HID * 4;
    int*   degT   = (int*)alloc((size_t)NN * 4);
    int*   degOff = (int*)alloc((size_t)NN * NREP * 4);
    int*   rowptr = (int*)alloc((size_t)NN * 4);
    float* dinv   = (float*)alloc((size_t)NN * 4);
    int*   bsum   = (int*)alloc(256 * 4);
    int*   eslot  = (int*)alloc((size_t)NE * 4);
    int2*  pairs  = (int2*)alloc((size_t)NEPAD * 8);
    float* t      = (float*)alloc((size_t)NN * HID * 4);
    float* rbuf   = (float*)alloc((size_t)NN * HID * 4);
    // swizzled bf16 hi/lo activations: x + 2 ping-pong sets
    const size_t ASZ = (size_t)ROWBLK_PAD * 4 * 512;  // elements
    unsigned short* xH = (unsigned short*)alloc(ASZ * 2);
    unsigned short* xL = (unsigned short*)alloc(ASZ * 2);
    unsigned short* hH0 = (unsigned short*)alloc(ASZ * 2);
    unsigned short* hL0 = (unsigned short*)alloc(ASZ * 2);
    unsigned short* hH1 = (unsigned short*)alloc(ASZ * 2);
    unsigned short* hL1 = (unsigned short*)alloc(ASZ * 2);
    // swizzled weights, 7 matrices
    unsigned short* bH = (unsigned short*)alloc((size_t)7 * 16384 * 2);
    unsigned short* bL = (unsigned short*)alloc((size_t)7 * 16384 * 2);

    hipMemsetAsync(deg8, 0, zspan, stream);

    k_front<<<FRONT_GRID, 256, 0, stream>>>(x, xH, xL, W0, Wh, Rh, bH, bL,
                                            ei, deg8, eslot);
    k_scan1<<<(NN + 255) / 256, 256, 0, stream>>>(deg8, degT, degOff, dinv, bsum);
    k_scan3<<<(NN + 255) / 256, 256, 0, stream>>>(degT, bsum, rowptr, pairs);

    // GEMM0 fused with CSR fill (independent work in one dispatch)
    k_gemm_mfma<1, true><<<GEMM_GRID + FILL_GRID, 256, 0, stream>>>(
        xH, xL, bH, bL, nullptr, nullptr, t, nullptr,
        ei, rowptr, eslot, degOff, dinv, pairs);

    const int spmmGrid = NN / 16;  // 3125 blocks x 1024 threads
    k_spmm<false, false><<<spmmGrid, 1024, 0, stream>>>(
        t, nullptr, rowptr, degT, pairs, dinv, b0, g0, be0, hH0, hL0,
        nullptr, nullptr);

    unsigned short* hh[2] = {hH0, hH1};
    unsigned short* hl[2] = {hL0, hL1};
    int cur = 0;
    for (int i = 0; i < LHID; ++i) {
        unsigned short* ih = hh[cur];
        unsigned short* il = hl[cur];
        unsigned short* oh = hh[cur ^ 1];
        unsigned short* ol = hl[cur ^ 1];
        const unsigned short* w1H = bH + (size_t)(1 + i) * 16384;
        const unsigned short* w1L = bL + (size_t)(1 + i) * 16384;
        const unsigned short* w2H = bH + (size_t)(4 + i) * 16384;
        const unsigned short* w2L = bL + (size_t)(4 + i) * 16384;
        k_gemm_mfma<2, false><<<GEMM_GRID, 256, 0, stream>>>(
            ih, il, w1H, w1L, w2H, w2L, t, rbuf,
            nullptr, nullptr, nullptr, nullptr, nullptr, nullptr);
        if (i < LHID - 1)
            k_spmm<true, false><<<spmmGrid, 1024, 0, stream>>>(
                t, rbuf, rowptr, degT, pairs, dinv, bh + i * HID, gh + i * HID,
                beh + i * HID, oh, ol, nullptr, nullptr);
        else
            k_spmm<true, true><<<spmmGrid, 1024, 0, stream>>>(
                t, rbuf, rowptr, degT, pairs, dinv, bh + i * HID, gh + i * HID,
                beh + i * HID, nullptr, nullptr, batch, pooled);
        cur ^= 1;
    }

    k_head<<<NGRAPH, 128, 0, stream>>>(pooled, mW1, mb1, mW2, mb2, out);
}

// Round 14
// 509.152 us; speedup vs baseline: 1.0972x; 1.0972x over previous
//
#include <hip/hip_runtime.h>
#include <cstdint>
#include <cstddef>

#define NN 50000
#define NE 800000
#define NEPAD (NE + 3 * NN)   // CSR rows padded to multiple of 4
#define HID 128
#define NGRAPH 64
#define NCLASS 10
#define LHID 3
#define NREP 8                // deg counter replicas

// 16-row fragment blocks: 50000/16 = 3125 exact; GEMM covers 782*4 = 3128
#define ROWBLK 3125
#define ROWBLK_PAD 3128
#define GEMM_GRID 782         // 64-row tiles
#define FILL_GRID 3125        // 800000 / 256
#define FRONT_DEG 3125        // deg blocks (FIRST: they are the long pole)
#define FRONT_A 3125          // convA blocks
#define FRONT_B 56            // convB blocks (8 x 7 mats)
#define FRONT_GRID (FRONT_DEG + FRONT_A + FRONT_B)

// 1/sqrt(1+1e-5), computed in double, rounded to f32
static constexpr float BN_INV = 0.9999950000374996f;

typedef __attribute__((ext_vector_type(8))) __bf16 bf16x8;
typedef __attribute__((ext_vector_type(4))) float floatx4;

// ---------------- bf16 split helpers ----------------

__device__ __forceinline__ unsigned int f32_to_bf16_rne(float f) {
    unsigned int u = __float_as_uint(f);
    return (u + 0x7FFFu + ((u >> 16) & 1u)) >> 16;
}
__device__ __forceinline__ float bf16_to_f32(unsigned int h) {
    return __uint_as_float(h << 16);
}
__device__ __forceinline__ void split2(float a, float b, unsigned int& hi,
                                       unsigned int& lo) {
    unsigned int h0 = f32_to_bf16_rne(a), h1 = f32_to_bf16_rne(b);
    unsigned int l0 = f32_to_bf16_rne(a - bf16_to_f32(h0));
    unsigned int l1 = f32_to_bf16_rne(b - bf16_to_f32(h1));
    hi = h0 | (h1 << 16);
    lo = l0 | (l1 << 16);
}

__device__ __forceinline__ void gl2lds16(const void* g, void* l) {
    __builtin_amdgcn_global_load_lds((__attribute__((address_space(1))) void*)g,
                                     (__attribute__((address_space(3))) void*)l,
                                     16, 0, 0);
}

// ---------------- front: deg (first!) + convA + convB ----------------------

__global__ void k_front(const float* __restrict__ x, unsigned short* __restrict__ xH,
                        unsigned short* __restrict__ xL,
                        const float* __restrict__ W0, const float* __restrict__ Wh,
                        const float* __restrict__ Rh, unsigned short* __restrict__ bH,
                        unsigned short* __restrict__ bL,
                        const int* __restrict__ ei, int* __restrict__ deg8,
                        int* __restrict__ eslot) {
    const int b = blockIdx.x;
    const int tid = threadIdx.x;
    if (b < FRONT_DEG) {
        // deg histogram with 8x replicated counters (contention /8) + slot record
        int e = b * 256 + tid;                  // < 800000 exact
        int d = ei[NE + e];
        int rep = e & (NREP - 1);
        eslot[e] = atomicAdd(&deg8[rep * NN + d], 1);
    } else if (b < FRONT_DEG + FRONT_A) {
        // convA: x (f32 row-major) -> swizzled bf16 hi/lo A-fragments.
        int u = (b - FRONT_DEG) * 256 + tid;
        int lane = u & 63;
        int blk = u >> 6;
        int kblk = blk & 3;
        int rowBlock = blk >> 2;
        int m = rowBlock * 16 + (lane & 15);
        int k = kblk * 32 + (lane >> 4) * 8;
        const float4* p = (const float4*)&x[(size_t)m * 128 + k];
        float4 v0 = p[0];
        float4 v1 = p[1];
        float vals[8] = {v0.x, v0.y, v0.z, v0.w, v1.x, v1.y, v1.z, v1.w};
        union { unsigned int i[4]; uint4 v; } H, L;
#pragma unroll
        for (int j = 0; j < 4; ++j) split2(vals[2 * j], vals[2 * j + 1], H.i[j], L.i[j]);
        *(uint4*)&xH[(size_t)u * 8] = H.v;
        *(uint4*)&xL[(size_t)u * 8] = L.v;
    } else {
        // convB: W [k][n] f32 -> swizzled fragments; 7 matrices.
        int cb = b - FRONT_DEG - FRONT_A;
        int mat = cb >> 3;
        const float* src = (mat == 0) ? W0
                         : (mat <= 3) ? (Wh + (size_t)(mat - 1) * 16384)
                                      : (Rh + (size_t)(mat - 4) * 16384);
        int u = (cb & 7) * 256 + tid;  // 0..2047
        int lane = u & 63;
        int blk = u >> 6;
        int kblk = blk & 3;
        int nb = blk >> 2;
        int n = nb * 16 + (lane & 15);
        int k = kblk * 32 + (lane >> 4) * 8;
        union { unsigned int i[4]; uint4 v; } H, L;
#pragma unroll
        for (int j = 0; j < 4; ++j) {
            float a = src[(size_t)(k + 2 * j) * 128 + n];
            float c = src[(size_t)(k + 2 * j + 1) * 128 + n];
            split2(a, c, H.i[j], L.i[j]);
        }
        size_t base = (size_t)mat * 16384 + (size_t)u * 8;
        *(uint4*)&bH[base] = H.v;
        *(uint4*)&bL[base] = L.v;
    }
}

// ---------------- scan1: replica reduce + per-rep offsets + dinv + bsum -----

__global__ void k_scan1(const int* __restrict__ deg8, int* __restrict__ degT,
                        int* __restrict__ degOff, float* __restrict__ dinv,
                        int* __restrict__ bsum) {
    __shared__ int s[256];
    int i = blockIdx.x * 256 + threadIdx.x;
    int dsum = 0;
    if (i < NN) {
        int off[NREP];
#pragma unroll
        for (int r = 0; r < NREP; ++r) {
            off[r] = dsum;
            dsum += deg8[r * NN + i];
        }
#pragma unroll
        for (int r = 0; r < NREP; ++r) degOff[i * NREP + r] = off[r];
        degT[i] = dsum;
        dinv[i] = rsqrtf((float)(dsum + 1));  // +1 self-loop
    }
    s[threadIdx.x] = (dsum + 3) & ~3;
    __syncthreads();
    for (int o = 128; o > 0; o >>= 1) {
        if (threadIdx.x < o) s[threadIdx.x] += s[threadIdx.x + o];
        __syncthreads();
    }
    if (threadIdx.x == 0) bsum[blockIdx.x] = s[0];
}

// ---------------- scan3: rowptr (inlines scan2) + CSR pad zeroing ----------

__global__ void k_scan3(const int* __restrict__ degT, const int* __restrict__ bsum,
                        int* __restrict__ rowptr, int* __restrict__ col,
                        float* __restrict__ cfv) {
    __shared__ int s[256];
    __shared__ int offS;
    const int bid = blockIdx.x;
    s[threadIdx.x] = (threadIdx.x < bid) ? bsum[threadIdx.x] : 0;
    __syncthreads();
    for (int o = 128; o > 0; o >>= 1) {
        if (threadIdx.x < o) s[threadIdx.x] += s[threadIdx.x + o];
        __syncthreads();
    }
    if (threadIdx.x == 0) offS = s[0];
    __syncthreads();
    const int off = offS;
    __syncthreads();
    int i = bid * 256 + threadIdx.x;
    int d = (i < NN) ? degT[i] : 0;
    int v = (d + 3) & ~3;
    s[threadIdx.x] = v;
    __syncthreads();
    for (int o = 1; o < 256; o <<= 1) {
        int tv = (threadIdx.x >= o) ? s[threadIdx.x - o] : 0;
        __syncthreads();
        s[threadIdx.x] += tv;
        __syncthreads();
    }
    if (i < NN) {
        int rp = off + s[threadIdx.x] - v;  // exclusive
        rowptr[i] = rp;
        // zero the pad slots (<=3 per row) -> no big memsets needed
        for (int p = rp + d; p < rp + v; ++p) { col[p] = 0; cfv[p] = 0.f; }
    }
}

// ---------------- MFMA GEMM: C1 = A @ B1 [, C2 = A @ B2], split-bf16 --------
// Inline body (device-function/generic-LDS form ICEs clang). FILL=true adds
// CSR-fill blocks past GEMM_GRID. 64x128 tile, 4 waves 2x2, wave tile 32x64.

template <int NB, bool FILL>
__global__ __launch_bounds__(256, 3) void k_gemm_mfma(
    const unsigned short* __restrict__ Ahi, const unsigned short* __restrict__ Alo,
    const unsigned short* __restrict__ B1hi, const unsigned short* __restrict__ B1lo,
    const unsigned short* __restrict__ B2hi, const unsigned short* __restrict__ B2lo,
    float* __restrict__ C1, float* __restrict__ C2,
    const int* __restrict__ ei, const int* __restrict__ rowptr,
    const int* __restrict__ eslot, const int* __restrict__ degOff,
    const float* __restrict__ dinv, int* __restrict__ col,
    float* __restrict__ cfv) {
    __shared__ unsigned short lds[(1 + 2 * NB) * 4096];
    if (FILL && blockIdx.x >= GEMM_GRID) {
        int e = (blockIdx.x - GEMM_GRID) * 256 + threadIdx.x;  // < 800000 exact
        int s = ei[e];
        int d = ei[NE + e];
        int rep = e & (NREP - 1);
        int p = rowptr[d] + degOff[d * NREP + rep] + eslot[e];
        col[p] = s;
        cfv[p] = dinv[s];
        return;
    }
    unsigned short* AhiS = lds;             // 2048
    unsigned short* AloS = lds + 2048;      // 2048
    unsigned short* B1hiS = lds + 4096;     // 4096
    unsigned short* B1loS = lds + 8192;     // 4096
    unsigned short* B2hiS = lds + 12288;    // NB==2 only
    unsigned short* B2loS = lds + 16384;

    const int tid = threadIdx.x;
    const int wave = tid >> 6;
    const int lane = tid & 63;
    const int wm = wave & 1;
    const int wn = wave >> 1;
    const int rb0 = blockIdx.x * 4;         // first 16-row block

    floatx4 acc1[2][4], acc2[2][4];
    floatx4 zero = {0.f, 0.f, 0.f, 0.f};
#pragma unroll
    for (int i = 0; i < 2; ++i)
#pragma unroll
        for (int j = 0; j < 4; ++j) { acc1[i][j] = zero; if (NB == 2) acc2[i][j] = zero; }

    for (int kc = 0; kc < 4; ++kc) {
        const int nit = (NB == 2) ? 10 : 6;  // units: A 8 + B 16*NB, / 4 waves
#pragma unroll
        for (int it = 0; it < nit; ++it) {
            int i = it * 4 + wave;
            const unsigned short* src;
            unsigned short* dst;
            if (i < 4)       { src = Ahi  + ((size_t)(rb0 + i) * 4 + kc) * 512;       dst = AhiS  + i * 512; }
            else if (i < 8)  { int rb = i - 4;  src = Alo  + ((size_t)(rb0 + rb) * 4 + kc) * 512; dst = AloS  + rb * 512; }
            else if (i < 16) { int nb = i - 8;  src = B1hi + ((size_t)nb * 4 + kc) * 512;         dst = B1hiS + nb * 512; }
            else if (i < 24) { int nb = i - 16; src = B1lo + ((size_t)nb * 4 + kc) * 512;         dst = B1loS + nb * 512; }
            else if (i < 32) { int nb = i - 24; src = B2hi + ((size_t)nb * 4 + kc) * 512;         dst = B2hiS + nb * 512; }
            else             { int nb = i - 32; src = B2lo + ((size_t)nb * 4 + kc) * 512;         dst = B2loS + nb * 512; }
            gl2lds16(src + (size_t)lane * 8, dst);
        }
        __syncthreads();

        bf16x8 aH[2], aL[2], bH[4], bL[4];
#pragma unroll
        for (int t = 0; t < 2; ++t)
            aH[t] = *(const bf16x8*)(AhiS + (wm * 2 + t) * 512 + lane * 8);
#pragma unroll
        for (int t = 0; t < 4; ++t)
            bH[t] = *(const bf16x8*)(B1hiS + (wn * 4 + t) * 512 + lane * 8);
#pragma unroll
        for (int tm = 0; tm < 2; ++tm)
#pragma unroll
            for (int tn = 0; tn < 4; ++tn)
                acc1[tm][tn] = __builtin_amdgcn_mfma_f32_16x16x32_bf16(
                    aH[tm], bH[tn], acc1[tm][tn], 0, 0, 0);
#pragma unroll
        for (int t = 0; t < 4; ++t)
            bL[t] = *(const bf16x8*)(B1loS + (wn * 4 + t) * 512 + lane * 8);
#pragma unroll
        for (int tm = 0; tm < 2; ++tm)
#pragma unroll
            for (int tn = 0; tn < 4; ++tn)
                acc1[tm][tn] = __builtin_amdgcn_mfma_f32_16x16x32_bf16(
                    aH[tm], bL[tn], acc1[tm][tn], 0, 0, 0);
#pragma unroll
        for (int t = 0; t < 2; ++t)
            aL[t] = *(const bf16x8*)(AloS + (wm * 2 + t) * 512 + lane * 8);
#pragma unroll
        for (int tm = 0; tm < 2; ++tm)
#pragma unroll
            for (int tn = 0; tn < 4; ++tn)
                acc1[tm][tn] = __builtin_amdgcn_mfma_f32_16x16x32_bf16(
                    aL[tm], bH[tn], acc1[tm][tn], 0, 0, 0);
        if (NB == 2) {
#pragma unroll
            for (int t = 0; t < 4; ++t)
                bH[t] = *(const bf16x8*)(B2hiS + (wn * 4 + t) * 512 + lane * 8);
#pragma unroll
            for (int tm = 0; tm < 2; ++tm)
#pragma unroll
                for (int tn = 0; tn < 4; ++tn)
                    acc2[tm][tn] = __builtin_amdgcn_mfma_f32_16x16x32_bf16(
                        aH[tm], bH[tn], acc2[tm][tn], 0, 0, 0);
#pragma unroll
            for (int tm = 0; tm < 2; ++tm)
#pragma unroll
                for (int tn = 0; tn < 4; ++tn)
                    acc2[tm][tn] = __builtin_amdgcn_mfma_f32_16x16x32_bf16(
                        aL[tm], bH[tn], acc2[tm][tn], 0, 0, 0);
#pragma unroll
            for (int t = 0; t < 4; ++t)
                bL[t] = *(const bf16x8*)(B2loS + (wn * 4 + t) * 512 + lane * 8);
#pragma unroll
            for (int tm = 0; tm < 2; ++tm)
#pragma unroll
                for (int tn = 0; tn < 4; ++tn)
                    acc2[tm][tn] = __builtin_amdgcn_mfma_f32_16x16x32_bf16(
                        aH[tm], bL[tn], acc2[tm][tn], 0, 0, 0);
        }
        __syncthreads();
    }

    // epilogue: C/D layout col = lane&15, row = (lane>>4)*4 + r
    const int quad = lane >> 4;
    const int col0 = lane & 15;
    const int rowBase = blockIdx.x * 64 + wm * 32;
#pragma unroll
    for (int tm = 0; tm < 2; ++tm) {
#pragma unroll
        for (int tn = 0; tn < 4; ++tn) {
            int c = wn * 64 + tn * 16 + col0;
#pragma unroll
            for (int r = 0; r < 4; ++r) {
                int row = rowBase + tm * 16 + quad * 4 + r;
                if (row < NN) {
                    C1[(size_t)row * 128 + c] = acc1[tm][tn][r];
                    if (NB == 2) C2[(size_t)row * 128 + c] = acc2[tm][tn][r];
                }
            }
        }
    }
}

// ---------------- SpMM + epilogue ------------------------------------------
// Block = 16 nodes via 16 WAVES (1024 threads), ONE node per wave — R12's
// proven shape (66 us, VGPR 32, 2 blocks/CU). Lane -> features (2l,2l+1);
// one 512 B contiguous row per gather instr; unroll 2 -> 8 rows in flight.
// Metadata: separate col int4 + cfv float4 (R13's interleaved pairs regressed
// occupancy 73->40%). non-LAST: LDS-staged swizzled output. LAST: fused pool.

template <bool RES, bool LAST>
__global__ __launch_bounds__(1024) void k_spmm(const float* __restrict__ t,
                                               const float* __restrict__ r,
                                               const int* __restrict__ rowptr,
                                               const int* __restrict__ degT,
                                               const int* __restrict__ col,
                                               const float* __restrict__ cfv,
                                               const float* __restrict__ dinv,
                                               const float* __restrict__ bias,
                                               const float* __restrict__ gamma,
                                               const float* __restrict__ beta,
                                               unsigned short* __restrict__ hHi,
                                               unsigned short* __restrict__ hLo,
                                               const int* __restrict__ batch,
                                               float* __restrict__ pooled) {
    __shared__ unsigned short shH[16][136];  // non-LAST only (+8 shorts pad)
    __shared__ unsigned short shL[16][136];
    __shared__ float shP[16][64][2];         // LAST only: per-wave partials
    const int lane = threadIdx.x & 63;
    const int wave = threadIdx.x >> 6;       // 0..15 = node within block
    const int f = lane * 2;
    const int node = blockIdx.x * 16 + wave; // grid = NN/16 exact

    const float2 bv = *(const float2*)&bias[f];
    const float2 gv = *(const float2*)&gamma[f];
    const float2 ev = *(const float2*)&beta[f];

    const int start = rowptr[node];          // multiple of 4, 16B-aligned
    const int cnt4 = (degT[node] + 3) >> 2;
    float ax = 0.f, ay = 0.f;
#pragma unroll 2
    for (int q = 0; q < cnt4; ++q) {
        int4 cs = *(const int4*)&col[start + q * 4];
        float4 wv = *(const float4*)&cfv[start + q * 4];
        float2 v0 = *(const float2*)&t[(size_t)cs.x * 128 + f];
        float2 v1 = *(const float2*)&t[(size_t)cs.y * 128 + f];
        float2 v2 = *(const float2*)&t[(size_t)cs.z * 128 + f];
        float2 v3 = *(const float2*)&t[(size_t)cs.w * 128 + f];
        ax = fmaf(wv.x, v0.x, ax); ay = fmaf(wv.x, v0.y, ay);
        ax = fmaf(wv.y, v1.x, ax); ay = fmaf(wv.y, v1.y, ay);
        ax = fmaf(wv.z, v2.x, ax); ay = fmaf(wv.z, v2.y, ay);
        ax = fmaf(wv.w, v3.x, ax); ay = fmaf(wv.w, v3.y, ay);
    }
    const float di = dinv[node];
    const float dii = di * di;
    float2 tv = *(const float2*)&t[(size_t)node * 128 + f];
    float cx = di * ax + dii * tv.x + bv.x;
    float cy = di * ay + dii * tv.y + bv.y;
    if (RES) {
        float2 rv = *(const float2*)&r[(size_t)node * 128 + f];
        cx += rv.x;
        cy += rv.y;
    }
    const float ox = fmaxf(cx * (BN_INV * gv.x) + ev.x, 0.f);
    const float oy = fmaxf(cy * (BN_INV * gv.y) + ev.y, 0.f);

    if (LAST) {
        bool uni = (batch[blockIdx.x * 16] == batch[blockIdx.x * 16 + 15]);
        if (uni) {
            shP[wave][lane][0] = ox;
            shP[wave][lane][1] = oy;
            __syncthreads();
            if (wave == 0) {
                float a = shP[0][lane][0], b = shP[0][lane][1];
#pragma unroll
                for (int w = 1; w < 16; ++w) {
                    a = fmaxf(a, shP[w][lane][0]);
                    b = fmaxf(b, shP[w][lane][1]);
                }
                int g = batch[blockIdx.x * 16];
                atomicMax((unsigned int*)&pooled[g * 128 + f], __float_as_uint(a));
                atomicMax((unsigned int*)&pooled[g * 128 + f + 1], __float_as_uint(b));
            }
        } else {
            int g = batch[node];
            atomicMax((unsigned int*)&pooled[g * 128 + f], __float_as_uint(ox));
            atomicMax((unsigned int*)&pooled[g * 128 + f + 1], __float_as_uint(oy));
        }
        return;
    }

    unsigned int H, L;
    split2(ox, oy, H, L);
    ((unsigned int*)&shH[wave][0])[lane] = H;
    ((unsigned int*)&shL[wave][0])[lane] = L;
    __syncthreads();

    // emit 4 hi + 4 lo units (1 KB each), fully coalesced; waves 0-7 emit.
    const int u = threadIdx.x >> 6;
    const int l = threadIdx.x & 63;
    const int m = l & 15;
    const int kg = l >> 4;
    if (u < 4) {
        uint4 H4 = *(const uint4*)&shH[m][u * 32 + kg * 8];
        ((uint4*)hHi)[((size_t)blockIdx.x * 4 + u) * 64 + l] = H4;
    } else if (u < 8) {
        int uu = u - 4;
        uint4 L4 = *(const uint4*)&shL[m][uu * 32 + kg * 8];
        ((uint4*)hLo)[((size_t)blockIdx.x * 4 + uu) * 64 + l] = L4;
    }
}

// ---------------- MLP head (64 parallel blocks) ----------------

__global__ void k_head(const float* __restrict__ pooled, const float* __restrict__ mW1,
                       const float* __restrict__ mb1, const float* __restrict__ mW2,
                       const float* __restrict__ mb2, float* __restrict__ out) {
    __shared__ float p[128];
    __shared__ float z[128];
    int g = blockIdx.x;
    int j = threadIdx.x;  // 128 threads
    p[j] = pooled[g * 128 + j];
    __syncthreads();
    float a = mb1[j];
#pragma unroll 8
    for (int k = 0; k < 128; ++k) a += p[k] * mW1[k * 128 + j];
    z[j] = fmaxf(a, 0.f);
    __syncthreads();
    if (j < NCLASS) {
        float o = mb2[j];
#pragma unroll 8
        for (int k = 0; k < 128; ++k) o += z[k] * mW2[k * NCLASS + j];
        out[g * NCLASS + j] = o;
    }
}

// ---------------- launcher ----------------

extern "C" void kernel_launch(void* const* d_in, const int* in_sizes, int n_in,
                              void* d_out, int out_size, void* d_ws, size_t ws_size,
                              hipStream_t stream) {
    const float* x   = (const float*)d_in[0];
    const int*   ei  = (const int*)d_in[1];
    const int* batch = (const int*)d_in[2];
    const float* W0  = (const float*)d_in[3];
    const float* b0  = (const float*)d_in[4];
    const float* g0  = (const float*)d_in[5];
    const float* be0 = (const float*)d_in[6];
    const float* Wh  = (const float*)d_in[7];
    const float* bh  = (const float*)d_in[8];
    const float* gh  = (const float*)d_in[9];
    const float* beh = (const float*)d_in[10];
    const float* Rh  = (const float*)d_in[11];
    const float* mW1 = (const float*)d_in[12];
    const float* mb1 = (const float*)d_in[13];
    const float* mW2 = (const float*)d_in[14];
    const float* mb2 = (const float*)d_in[15];
    float* out = (float*)d_out;

    char* ws = (char*)d_ws;
    size_t off = 0;
    auto alloc = [&](size_t bytes) -> void* {
        void* p = ws + off;
        off += (bytes + 255) & ~(size_t)255;
        return p;
    };
    // deg8 + pooled adjacent -> single memset covers both
    int*   deg8   = (int*)alloc((size_t)NREP * NN * 4);
    float* pooled = (float*)alloc((size_t)NGRAPH * HID * 4);
    size_t zspan = (size_t)((char*)pooled - (char*)deg8) + (size_t)NGRAPH * HID * 4;
    int*   degT   = (int*)alloc((size_t)NN * 4);
    int*   degOff = (int*)alloc((size_t)NN * NREP * 4);
    int*   rowptr = (int*)alloc((size_t)NN * 4);
    float* dinv   = (float*)alloc((size_t)NN * 4);
    int*   bsum   = (int*)alloc(256 * 4);
    int*   eslot  = (int*)alloc((size_t)NE * 4);
    int*   col    = (int*)alloc((size_t)NEPAD * 4);
    float* cfv    = (float*)alloc((size_t)NEPAD * 4);
    float* t      = (float*)alloc((size_t)NN * HID * 4);
    float* rbuf   = (float*)alloc((size_t)NN * HID * 4);
    // swizzled bf16 hi/lo activations: x + 2 ping-pong sets
    const size_t ASZ = (size_t)ROWBLK_PAD * 4 * 512;  // elements
    unsigned short* xH = (unsigned short*)alloc(ASZ * 2);
    unsigned short* xL = (unsigned short*)alloc(ASZ * 2);
    unsigned short* hH0 = (unsigned short*)alloc(ASZ * 2);
    unsigned short* hL0 = (unsigned short*)alloc(ASZ * 2);
    unsigned short* hH1 = (unsigned short*)alloc(ASZ * 2);
    unsigned short* hL1 = (unsigned short*)alloc(ASZ * 2);
    // swizzled weights, 7 matrices
    unsigned short* bH = (unsigned short*)alloc((size_t)7 * 16384 * 2);
    unsigned short* bL = (unsigned short*)alloc((size_t)7 * 16384 * 2);

    hipMemsetAsync(deg8, 0, zspan, stream);

    k_front<<<FRONT_GRID, 256, 0, stream>>>(x, xH, xL, W0, Wh, Rh, bH, bL,
                                            ei, deg8, eslot);
    k_scan1<<<(NN + 255) / 256, 256, 0, stream>>>(deg8, degT, degOff, dinv, bsum);
    k_scan3<<<(NN + 255) / 256, 256, 0, stream>>>(degT, bsum, rowptr, col, cfv);

    // GEMM0 fused with CSR fill (independent work in one dispatch)
    k_gemm_mfma<1, true><<<GEMM_GRID + FILL_GRID, 256, 0, stream>>>(
        xH, xL, bH, bL, nullptr, nullptr, t, nullptr,
        ei, rowptr, eslot, degOff, dinv, col, cfv);

    const int spmmGrid = NN / 16;  // 3125 blocks x 1024 threads
    k_spmm<false, false><<<spmmGrid, 1024, 0, stream>>>(
        t, nullptr, rowptr, degT, col, cfv, dinv, b0, g0, be0, hH0, hL0,
        nullptr, nullptr);

    unsigned short* hh[2] = {hH0, hH1};
    unsigned short* hl[2] = {hL0, hL1};
    int cur = 0;
    for (int i = 0; i < LHID; ++i) {
        unsigned short* ih = hh[cur];
        unsigned short* il = hl[cur];
        unsigned short* oh = hh[cur ^ 1];
        unsigned short* ol = hl[cur ^ 1];
        const unsigned short* w1H = bH + (size_t)(1 + i) * 16384;
        const unsigned short* w1L = bL + (size_t)(1 + i) * 16384;
        const unsigned short* w2H = bH + (size_t)(4 + i) * 16384;
        const unsigned short* w2L = bL + (size_t)(4 + i) * 16384;
        k_gemm_mfma<2, false><<<GEMM_GRID, 256, 0, stream>>>(
            ih, il, w1H, w1L, w2H, w2L, t, rbuf,
            nullptr, nullptr, nullptr, nullptr, nullptr, nullptr, nullptr);
        if (i < LHID - 1)
            k_spmm<true, false><<<spmmGrid, 1024, 0, stream>>>(
                t, rbuf, rowptr, degT, col, cfv, dinv, bh + i * HID, gh + i * HID,
                beh + i * HID, oh, ol, nullptr, nullptr);
        else
            k_spmm<true, true><<<spmmGrid, 1024, 0, stream>>>(
                t, rbuf, rowptr, degT, col, cfv, dinv, bh + i * HID, gh + i * HID,
                beh + i * HID, nullptr, nullptr, batch, pooled);
        cur ^= 1;
    }

    k_head<<<NGRAPH, 128, 0, stream>>>(pooled, mW1, mb1, mW2, mb2, out);
}